// Round 1
// baseline (314.403 us; speedup 1.0000x reference)
//
#include <hip/hip_runtime.h>
#include <math.h>

typedef __bf16 bf16x8 __attribute__((ext_vector_type(8)));
typedef float f32x4 __attribute__((ext_vector_type(4)));
typedef unsigned short u16;
typedef u16 u16x8 __attribute__((ext_vector_type(8)));

// clip(round(x/s), -128, 127)  -- rintf = round-half-even, matches jnp.round
__device__ __forceinline__ float quantq(float x, float s) {
    return fminf(fmaxf(rintf(x / s), -128.f), 127.f);
}

__device__ __forceinline__ u16 sign_bf16(float w) {
    return (w > 0.f) ? (u16)0x3F80 : ((w < 0.f) ? (u16)0xBF80 : (u16)0);
}

// ---------------- prep 1: alphas = mean(|w|) (deterministic tree reduce) ----
__global__ void alpha_kernel(const float* __restrict__ w1,
                             const float* __restrict__ w2,
                             const float* __restrict__ w3,
                             float* __restrict__ alphas) {
    __shared__ float red[256];
    const int b = blockIdx.x;
    const float* w = (b == 0) ? w1 : ((b == 1) ? w2 : w3);
    const int n = (b == 0) ? 784 * 128 : ((b == 1) ? 128 * 128 : 128 * 10);
    float s = 0.f;
    for (int i = threadIdx.x; i < n; i += 256) s += fabsf(w[i]);
    red[threadIdx.x] = s;
    __syncthreads();
    for (int off = 128; off > 0; off >>= 1) {
        if ((int)threadIdx.x < off) red[threadIdx.x] += red[threadIdx.x + off];
        __syncthreads();
    }
    if (threadIdx.x == 0) alphas[b] = red[0] / (float)n;
}

// ---------------- prep 2: pack sign(w) as bf16 +-1, fragment-ready ----------
// dest layout per kstep(K=32): [ntile][lane][8] where for B-operand of
// mfma_f32_16x16x32_bf16: lane = (kk/8)*16 + (col%16), j = kk%8
// Wb1: K padded 784->800 (25 ksteps, 8 ntiles)   = 102400 u16
// Wb2: K=128 (4 ksteps, 8 ntiles)                =  16384 u16
// Wb3: K=128 (4 ksteps, 1 ntile), N padded 10->16 =  2048 u16
__global__ void pack_kernel(const float* __restrict__ w1,
                            const float* __restrict__ w2,
                            const float* __restrict__ w3,
                            u16* __restrict__ Wb1) {
    u16* Wb2 = Wb1 + 102400;
    u16* Wb3 = Wb2 + 16384;
    int idx = blockIdx.x * 256 + threadIdx.x;
    if (idx < 102400) {
        int k = idx >> 7, n = idx & 127;
        u16 v = (k < 784) ? sign_bf16(w1[k * 128 + n]) : (u16)0;
        int dest = ((((k >> 5) * 8 + (n >> 4)) * 64) + ((((k & 31) >> 3) << 4) | (n & 15))) * 8 + (k & 7);
        Wb1[dest] = v;
    } else if (idx < 102400 + 16384) {
        int i = idx - 102400;
        int k = i >> 7, n = i & 127;
        u16 v = sign_bf16(w2[k * 128 + n]);
        int dest = ((((k >> 5) * 8 + (n >> 4)) * 64) + ((((k & 31) >> 3) << 4) | (n & 15))) * 8 + (k & 7);
        Wb2[dest] = v;
    } else if (idx < 102400 + 16384 + 2048) {
        int i = idx - 102400 - 16384;
        int k = i >> 4, n = i & 15;
        u16 v = (n < 10) ? sign_bf16(w3[k * 10 + n]) : (u16)0;
        int dest = (((k >> 5) * 64) + ((((k & 31) >> 3) << 4) | n)) * 8 + (k & 7);
        Wb3[dest] = v;
    }
}

// ---------------- fused forward: 64 rows/block, 4 waves ---------------------
__global__ __launch_bounds__(256) void fused_kernel(
    const float* __restrict__ input,
    const float* __restrict__ bias1, const float* __restrict__ bias2,
    const float* __restrict__ bias3,
    const float* __restrict__ ps_in, const float* __restrict__ ps1i,
    const float* __restrict__ ps1o, const float* __restrict__ ps2i,
    const float* __restrict__ ps2o, const float* __restrict__ ps3i,
    const float* __restrict__ ps3o,
    const float* __restrict__ alphas, const u16* __restrict__ Wb1,
    float* __restrict__ out0, float* __restrict__ h0, float* __restrict__ h1,
    float* __restrict__ h2, float* __restrict__ h3)
{
    const u16* Wb2 = Wb1 + 102400;
    const u16* Wb3 = Wb2 + 16384;

    // frag-ready LDS:
    __shared__ u16 A1[2048];  // [wave(4)][lane(64)][8]  : 64 rows x 32 k
    __shared__ u16 B1[4096];  // [ntile(8)][lane(64)][8] : 32 k x 128 n
    __shared__ u16 A2[8192];  // [ks(4)][wave(4)][lane(64)][8] : 64 rows x 128 k

    const int tid = threadIdx.x;
    const int wave = tid >> 6, lane = tid & 63;
    const int row0 = blockIdx.x * 64;

    const float s_in = *ps_in, s1i = *ps1i, s1o = *ps1o;
    const float s2i = *ps2i, s2o = *ps2o, s3i = *ps3i, s3o = *ps3o;
    const float alpha1 = alphas[0], alpha2 = alphas[1], alpha3 = alphas[2];

    f32x4 acc1[8];
#pragma unroll
    for (int n = 0; n < 8; ++n) acc1[n] = f32x4{0.f, 0.f, 0.f, 0.f};

    // staging decomposition: thread -> (row r, 8-col group g)
    const int r = tid >> 2;
    const int g = tid & 3;
    const int grow = row0 + r;

    // ---- layer 1: K-loop over 800 (25 x 32) ----
    for (int ksq = 0; ksq < 25; ++ksq) {
        const int k0 = ksq * 32;
        const int gcol = k0 + g * 8;

        // stage A (quantize input, emit h0)
        u16x8 qbits;
        if (gcol + 8 <= 784) {
            const float4 v0 = *reinterpret_cast<const float4*>(input + (size_t)grow * 784 + gcol);
            const float4 v1 = *reinterpret_cast<const float4*>(input + (size_t)grow * 784 + gcol + 4);
            float vv[8] = {v0.x, v0.y, v0.z, v0.w, v1.x, v1.y, v1.z, v1.w};
            float q[8];
#pragma unroll
            for (int j = 0; j < 8; ++j) q[j] = quantq(vv[j], s_in);
            float4 ha = {q[0] * s_in, q[1] * s_in, q[2] * s_in, q[3] * s_in};
            float4 hb = {q[4] * s_in, q[5] * s_in, q[6] * s_in, q[7] * s_in};
            *reinterpret_cast<float4*>(h0 + (size_t)grow * 784 + gcol) = ha;
            *reinterpret_cast<float4*>(h0 + (size_t)grow * 784 + gcol + 4) = hb;
#pragma unroll
            for (int j = 0; j < 8; ++j) qbits[j] = (u16)(__float_as_uint(q[j]) >> 16);
        } else {
#pragma unroll
            for (int j = 0; j < 8; ++j) qbits[j] = 0;
        }
        // A-frag dest: lane' = g*16 + (r&15), wave' = r>>4
        *reinterpret_cast<u16x8*>(&A1[(((r >> 4) * 64) + (g * 16) + (r & 15)) * 8]) = qbits;

        // stage B (linear copy of frag-ready chunk, 32B/thread)
        {
            const u16x8* s8 = reinterpret_cast<const u16x8*>(Wb1 + (size_t)ksq * 4096 + tid * 16);
            u16x8* d8 = reinterpret_cast<u16x8*>(&B1[tid * 16]);
            d8[0] = s8[0];
            d8[1] = s8[1];
        }
        __syncthreads();

        const bf16x8 a = *reinterpret_cast<const bf16x8*>(&A1[(wave * 64 + lane) * 8]);
#pragma unroll
        for (int n = 0; n < 8; ++n) {
            const bf16x8 b = *reinterpret_cast<const bf16x8*>(&B1[(n * 64 + lane) * 8]);
            acc1[n] = __builtin_amdgcn_mfma_f32_16x16x32_bf16(a, b, acc1[n], 0, 0, 0);
        }
        __syncthreads();
    }

    // ---- layer 1 epilogue: requantize, write h1, restage A2 (wave-local) ----
    const int cl = lane & 15;
    const int rh = lane >> 4;
    {
        const float a1s = alpha1 * s_in;
#pragma unroll
        for (int n = 0; n < 8; ++n) {
            const int col = n * 16 + cl;
            const float bias = bias1[col];
            const int ks = n >> 1;
            const int gk = ((n & 1) * 2) + (cl >> 3);
            const int jd = cl & 7;
#pragma unroll
            for (int j = 0; j < 4; ++j) {
                const int rl = rh * 4 + j;
                float x = a1s * acc1[n][j] + bias;
                x = quantq(x, s1i) * s1i;
                x = fmaxf(x, 0.f);
                const float qv = quantq(x, s1o);
                h1[(size_t)(row0 + wave * 16 + rl) * 128 + col] = qv * s1o;
                A2[(((ks * 4 + wave) * 64) + (gk * 16 + rl)) * 8 + jd] =
                    (u16)(__float_as_uint(qv) >> 16);
            }
        }
    }

    // ---- layer 2: K=128 (4 ksteps), B-frags straight from global (L2) ----
    f32x4 acc2[8];
#pragma unroll
    for (int n = 0; n < 8; ++n) acc2[n] = f32x4{0.f, 0.f, 0.f, 0.f};
#pragma unroll
    for (int ks = 0; ks < 4; ++ks) {
        const bf16x8 a = *reinterpret_cast<const bf16x8*>(&A2[((ks * 4 + wave) * 64 + lane) * 8]);
#pragma unroll
        for (int n = 0; n < 8; ++n) {
            const bf16x8 b = *reinterpret_cast<const bf16x8*>(Wb2 + ((size_t)(ks * 8 + n) * 64 + lane) * 8);
            acc2[n] = __builtin_amdgcn_mfma_f32_16x16x32_bf16(a, b, acc2[n], 0, 0, 0);
        }
    }

    // ---- layer 2 epilogue ----
    {
        const float a2s = alpha2 * s1o;
#pragma unroll
        for (int n = 0; n < 8; ++n) {
            const int col = n * 16 + cl;
            const float bias = bias2[col];
            const int ks = n >> 1;
            const int gk = ((n & 1) * 2) + (cl >> 3);
            const int jd = cl & 7;
#pragma unroll
            for (int j = 0; j < 4; ++j) {
                const int rl = rh * 4 + j;
                float x = a2s * acc2[n][j] + bias;
                x = quantq(x, s2i) * s2i;
                x = fmaxf(x, 0.f);
                const float qv = quantq(x, s2o);
                h2[(size_t)(row0 + wave * 16 + rl) * 128 + col] = qv * s2o;
                A2[(((ks * 4 + wave) * 64) + (gk * 16 + rl)) * 8 + jd] =
                    (u16)(__float_as_uint(qv) >> 16);
            }
        }
    }

    // ---- layer 3: K=128, single ntile (N=10 padded to 16) ----
    f32x4 acc3 = f32x4{0.f, 0.f, 0.f, 0.f};
#pragma unroll
    for (int ks = 0; ks < 4; ++ks) {
        const bf16x8 a = *reinterpret_cast<const bf16x8*>(&A2[((ks * 4 + wave) * 64 + lane) * 8]);
        const bf16x8 b = *reinterpret_cast<const bf16x8*>(Wb3 + ((size_t)ks * 64 + lane) * 8);
        acc3 = __builtin_amdgcn_mfma_f32_16x16x32_bf16(a, b, acc3, 0, 0, 0);
    }

    // ---- layer 3 epilogue: sigmoid + quant, write h3 and out0 ----
    if (cl < 10) {
        const float a3s = alpha3 * s2o;
        const float bias = bias3[cl];
#pragma unroll
        for (int j = 0; j < 4; ++j) {
            const int rgl = row0 + wave * 16 + rh * 4 + j;
            float x = a3s * acc3[j] + bias;
            x = quantq(x, s3i) * s3i;
            const float sg = 1.f / (1.f + expf(-x));
            const float qv = quantq(sg, s3o) * s3o;
            out0[(size_t)rgl * 10 + cl] = qv;
            h3[(size_t)rgl * 10 + cl] = qv;
        }
    }
}

extern "C" void kernel_launch(void* const* d_in, const int* in_sizes, int n_in,
                              void* d_out, int out_size, void* d_ws, size_t ws_size,
                              hipStream_t stream) {
    const float* input = (const float*)d_in[0];
    const float* w1    = (const float*)d_in[1];
    const float* bias1 = (const float*)d_in[2];
    const float* w2    = (const float*)d_in[3];
    const float* bias2 = (const float*)d_in[4];
    const float* w3    = (const float*)d_in[5];
    const float* bias3 = (const float*)d_in[6];
    const float* s_in  = (const float*)d_in[7];
    const float* s1i   = (const float*)d_in[8];
    const float* s1o   = (const float*)d_in[9];
    const float* s2i   = (const float*)d_in[10];
    const float* s2o   = (const float*)d_in[11];
    const float* s3i   = (const float*)d_in[12];
    const float* s3o   = (const float*)d_in[13];

    float* out = (float*)d_out;
    // output order: (x_final, h0, h1, h2, h3)
    float* out0 = out;
    float* h0 = out + 655360;                   // 65536*10
    float* h1 = out + 52035584;                 // + 65536*784
    float* h2 = out + 60424192;                 // + 65536*128
    float* h3 = out + 68812800;                 // + 65536*128

    float* alphas = (float*)d_ws;
    u16* Wb1 = (u16*)((char*)d_ws + 256);       // 102400+16384+2048 u16 = ~242KB total ws

    alpha_kernel<<<3, 256, 0, stream>>>(w1, w2, w3, alphas);
    pack_kernel<<<472, 256, 0, stream>>>(w1, w2, w3, Wb1);
    fused_kernel<<<1024, 256, 0, stream>>>(input, bias1, bias2, bias3,
                                           s_in, s1i, s1o, s2i, s2o, s3i, s3o,
                                           alphas, Wb1,
                                           out0, h0, h1, h2, h3);
}

// Round 2
// 121.952 us; speedup vs baseline: 2.5781x; 2.5781x over previous
//
#include <hip/hip_runtime.h>
#include <math.h>

typedef __bf16 bf16x8 __attribute__((ext_vector_type(8)));
typedef float f32x4 __attribute__((ext_vector_type(4)));
typedef unsigned short u16;
typedef u16 u16x8 __attribute__((ext_vector_type(8)));

// clip(round(x*inv), -128, 127) -- rintf = round-half-even, matches jnp.round
__device__ __forceinline__ float quantq_inv(float x, float inv) {
    return fminf(fmaxf(rintf(x * inv), -128.f), 127.f);
}

__device__ __forceinline__ u16 sign_bf16(float w) {
    return (w > 0.f) ? (u16)0x3F80 : ((w < 0.f) ? (u16)0xBF80 : (u16)0);
}

// ---------------- prep 1a: per-slice |w| partial sums (deterministic) -------
__global__ void alpha_part(const float* __restrict__ w1,
                           const float* __restrict__ w2,
                           const float* __restrict__ w3,
                           float* __restrict__ partial) {
    __shared__ float red[256];
    const int bid = blockIdx.x;
    const int m = bid >> 5, i = bid & 31;
    const float* w = (m == 0) ? w1 : ((m == 1) ? w2 : w3);
    const int n = (m == 0) ? 100352 : ((m == 1) ? 16384 : 1280);
    const int chunk = n >> 5;  // all divisible by 32
    const float* p = w + i * chunk;
    float s = 0.f;
    for (int t = threadIdx.x; t < chunk; t += 256) s += fabsf(p[t]);
    red[threadIdx.x] = s;
    __syncthreads();
    for (int off = 128; off > 0; off >>= 1) {
        if ((int)threadIdx.x < off) red[threadIdx.x] += red[threadIdx.x + off];
        __syncthreads();
    }
    if (threadIdx.x == 0) partial[bid] = red[0];
}

// ---------------- prep 1b: final alpha = sum(partials)/n --------------------
__global__ void alpha_final(const float* __restrict__ partial,
                            float* __restrict__ alphas) {
    const int t = threadIdx.x;
    if (t < 3) {
        float s = 0.f;
        for (int i = 0; i < 32; ++i) s += partial[t * 32 + i];
        const int n = (t == 0) ? 100352 : ((t == 1) ? 16384 : 1280);
        alphas[t] = s / (float)n;
    }
}

// ---------------- prep 2: pack sign(w) as bf16 +-1, fragment-ready ----------
// dest layout per kstep(K=32): [ntile][lane][8] where for B-operand of
// mfma_f32_16x16x32_bf16: lane = (kk/8)*16 + (col%16), j = kk%8
// Wb1: K padded 784->800 (25 ksteps, 8 ntiles)   = 102400 u16
// Wb2: K=128 (4 ksteps, 8 ntiles)                =  16384 u16
// Wb3: K=128 (4 ksteps, 1 ntile), N padded 10->16 =  2048 u16
__global__ void pack_kernel(const float* __restrict__ w1,
                            const float* __restrict__ w2,
                            const float* __restrict__ w3,
                            u16* __restrict__ Wb1) {
    u16* Wb2 = Wb1 + 102400;
    u16* Wb3 = Wb2 + 16384;
    int idx = blockIdx.x * 256 + threadIdx.x;
    if (idx < 102400) {
        int k = idx >> 7, n = idx & 127;
        u16 v = (k < 784) ? sign_bf16(w1[k * 128 + n]) : (u16)0;
        int dest = ((((k >> 5) * 8 + (n >> 4)) * 64) + ((((k & 31) >> 3) << 4) | (n & 15))) * 8 + (k & 7);
        Wb1[dest] = v;
    } else if (idx < 102400 + 16384) {
        int i = idx - 102400;
        int k = i >> 7, n = i & 127;
        u16 v = sign_bf16(w2[k * 128 + n]);
        int dest = ((((k >> 5) * 8 + (n >> 4)) * 64) + ((((k & 31) >> 3) << 4) | (n & 15))) * 8 + (k & 7);
        Wb2[dest] = v;
    } else if (idx < 102400 + 16384 + 2048) {
        int i = idx - 102400 - 16384;
        int k = i >> 4, n = i & 15;
        u16 v = (n < 10) ? sign_bf16(w3[k * 10 + n]) : (u16)0;
        int dest = (((k >> 5) * 64) + ((((k & 31) >> 3) << 4) | n)) * 8 + (k & 7);
        Wb3[dest] = v;
    }
}

// ---------------- fused forward: 64 rows/block, 4 waves, ZERO barriers ------
__global__ __launch_bounds__(256) void fused_kernel(
    const float* __restrict__ input,
    const float* __restrict__ bias1, const float* __restrict__ bias2,
    const float* __restrict__ bias3,
    const float* __restrict__ ps_in, const float* __restrict__ ps1i,
    const float* __restrict__ ps1o, const float* __restrict__ ps2i,
    const float* __restrict__ ps2o, const float* __restrict__ ps3i,
    const float* __restrict__ ps3o,
    const float* __restrict__ alphas, const u16* __restrict__ Wb1,
    float* __restrict__ out0, float* __restrict__ h0, float* __restrict__ h1,
    float* __restrict__ h2, float* __restrict__ h3)
{
    const u16* Wb2 = Wb1 + 102400;
    const u16* Wb3 = Wb2 + 16384;

    // wave-local inter-layer exchange only (no block barriers anywhere)
    __shared__ u16 A2[8192];  // [ks(4)][wave(4)][lane(64)][8] : 64 rows x 128 k

    const int tid = threadIdx.x;
    const int wave = tid >> 6, lane = tid & 63;
    const int row0 = blockIdx.x * 64;

    const float s_in = *ps_in, s1i = *ps1i, s1o = *ps1o;
    const float s2i = *ps2i, s2o = *ps2o, s3i = *ps3i, s3o = *ps3o;
    const float inv_sin = 1.f / s_in, inv_s1i = 1.f / s1i, inv_s1o = 1.f / s1o;
    const float inv_s2i = 1.f / s2i, inv_s2o = 1.f / s2o;
    const float inv_s3i = 1.f / s3i, inv_s3o = 1.f / s3o;
    const float alpha1 = alphas[0], alpha2 = alphas[1], alpha3 = alphas[2];

    // A-frag ownership: row = lane&15 (within wave's 16-row tile), kgroup = lane>>4
    const int rA = lane & 15;
    const int gA = lane >> 4;
    const size_t arow = (size_t)(row0 + wave * 16 + rA) * 784;

    f32x4 acc1[8];
#pragma unroll
    for (int n = 0; n < 8; ++n) acc1[n] = f32x4{0.f, 0.f, 0.f, 0.f};

    // ---- layer 1: K=784 padded to 800 (25 ksteps), no LDS, no barriers ----
    f32x4 pv0, pv1;
    {
        const float* p = input + arow + gA * 8;
        pv0 = *reinterpret_cast<const f32x4*>(p);
        pv1 = *reinterpret_cast<const f32x4*>(p + 4);
    }
    const u16* bw1 = Wb1 + (size_t)lane * 8;

    for (int ksq = 0; ksq < 25; ++ksq) {
        float v[8];
#pragma unroll
        for (int j = 0; j < 4; ++j) { v[j] = pv0[j]; v[4 + j] = pv1[j]; }
        const bool valid = (ksq < 24) || (gA < 2);

        // software prefetch next kstep's A data
        if (ksq < 24) {
            const int cb = (ksq + 1) * 32 + gA * 8;
            if (cb + 8 <= 784) {
                const float* p = input + arow + cb;
                pv0 = *reinterpret_cast<const f32x4*>(p);
                pv1 = *reinterpret_cast<const f32x4*>(p + 4);
            }
        }

        u16x8 qb;
        if (valid) {
            float q[8];
#pragma unroll
            for (int j = 0; j < 8; ++j) q[j] = quantq_inv(v[j], inv_sin);
            f32x4 ha = {q[0] * s_in, q[1] * s_in, q[2] * s_in, q[3] * s_in};
            f32x4 hb = {q[4] * s_in, q[5] * s_in, q[6] * s_in, q[7] * s_in};
            float* hp = h0 + arow + ksq * 32 + gA * 8;
            __builtin_nontemporal_store(ha, reinterpret_cast<f32x4*>(hp));
            __builtin_nontemporal_store(hb, reinterpret_cast<f32x4*>(hp + 4));
#pragma unroll
            for (int j = 0; j < 8; ++j) qb[j] = (u16)(__float_as_uint(q[j]) >> 16);
        } else {
#pragma unroll
            for (int j = 0; j < 8; ++j) qb[j] = (u16)0;
        }
        union { u16x8 u; bf16x8 b; } cvt;
        cvt.u = qb;
        const bf16x8 a = cvt.b;

        const u16* bp = bw1 + (size_t)ksq * 4096;
#pragma unroll
        for (int n = 0; n < 8; ++n) {
            const bf16x8 b = *reinterpret_cast<const bf16x8*>(bp + n * 512);
            acc1[n] = __builtin_amdgcn_mfma_f32_16x16x32_bf16(a, b, acc1[n], 0, 0, 0);
        }
    }

    // ---- layer 1 epilogue: requantize, write h1, restage A2 (wave-local) ----
    const int cl = lane & 15;
    const int rh = lane >> 4;
    {
        const float a1s = alpha1 * s_in;
#pragma unroll
        for (int n = 0; n < 8; ++n) {
            const int col = n * 16 + cl;
            const float bias = bias1[col];
            const int ks = n >> 1;
            const int gk = ((n & 1) * 2) + (cl >> 3);
            const int jd = cl & 7;
#pragma unroll
            for (int j = 0; j < 4; ++j) {
                const int rl = rh * 4 + j;
                float x = a1s * acc1[n][j] + bias;
                x = quantq_inv(x, inv_s1i) * s1i;
                x = fmaxf(x, 0.f);
                const float qv = quantq_inv(x, inv_s1o);
                __builtin_nontemporal_store(qv * s1o,
                    h1 + (size_t)(row0 + wave * 16 + rl) * 128 + col);
                A2[(((ks * 4 + wave) * 64) + (gk * 16 + rl)) * 8 + jd] =
                    (u16)(__float_as_uint(qv) >> 16);
            }
        }
    }

    // ---- layer 2: K=128 (4 ksteps), B-frags straight from global (L1) ----
    f32x4 acc2[8];
#pragma unroll
    for (int n = 0; n < 8; ++n) acc2[n] = f32x4{0.f, 0.f, 0.f, 0.f};
#pragma unroll
    for (int ks = 0; ks < 4; ++ks) {
        const bf16x8 a = *reinterpret_cast<const bf16x8*>(&A2[((ks * 4 + wave) * 64 + lane) * 8]);
#pragma unroll
        for (int n = 0; n < 8; ++n) {
            const bf16x8 b = *reinterpret_cast<const bf16x8*>(Wb2 + ((size_t)(ks * 8 + n) * 64 + lane) * 8);
            acc2[n] = __builtin_amdgcn_mfma_f32_16x16x32_bf16(a, b, acc2[n], 0, 0, 0);
        }
    }

    // ---- layer 2 epilogue ----
    {
        const float a2s = alpha2 * s1o;
#pragma unroll
        for (int n = 0; n < 8; ++n) {
            const int col = n * 16 + cl;
            const float bias = bias2[col];
            const int ks = n >> 1;
            const int gk = ((n & 1) * 2) + (cl >> 3);
            const int jd = cl & 7;
#pragma unroll
            for (int j = 0; j < 4; ++j) {
                const int rl = rh * 4 + j;
                float x = a2s * acc2[n][j] + bias;
                x = quantq_inv(x, inv_s2i) * s2i;
                x = fmaxf(x, 0.f);
                const float qv = quantq_inv(x, inv_s2o);
                __builtin_nontemporal_store(qv * s2o,
                    h2 + (size_t)(row0 + wave * 16 + rl) * 128 + col);
                A2[(((ks * 4 + wave) * 64) + (gk * 16 + rl)) * 8 + jd] =
                    (u16)(__float_as_uint(qv) >> 16);
            }
        }
    }

    // ---- layer 3: K=128, single ntile (N=10 padded to 16) ----
    f32x4 acc3 = f32x4{0.f, 0.f, 0.f, 0.f};
#pragma unroll
    for (int ks = 0; ks < 4; ++ks) {
        const bf16x8 a = *reinterpret_cast<const bf16x8*>(&A2[((ks * 4 + wave) * 64 + lane) * 8]);
        const bf16x8 b = *reinterpret_cast<const bf16x8*>(Wb3 + ((size_t)ks * 64 + lane) * 8);
        acc3 = __builtin_amdgcn_mfma_f32_16x16x32_bf16(a, b, acc3, 0, 0, 0);
    }

    // ---- layer 3 epilogue: sigmoid + quant, write h3 and out0 ----
    if (cl < 10) {
        const float a3s = alpha3 * s2o;
        const float bias = bias3[cl];
#pragma unroll
        for (int j = 0; j < 4; ++j) {
            const int rgl = row0 + wave * 16 + rh * 4 + j;
            float x = a3s * acc3[j] + bias;
            x = quantq_inv(x, inv_s3i) * s3i;
            const float sg = 1.f / (1.f + expf(-x));
            const float qv = quantq_inv(sg, inv_s3o) * s3o;
            out0[(size_t)rgl * 10 + cl] = qv;
            h3[(size_t)rgl * 10 + cl] = qv;
        }
    }
}

extern "C" void kernel_launch(void* const* d_in, const int* in_sizes, int n_in,
                              void* d_out, int out_size, void* d_ws, size_t ws_size,
                              hipStream_t stream) {
    const float* input = (const float*)d_in[0];
    const float* w1    = (const float*)d_in[1];
    const float* bias1 = (const float*)d_in[2];
    const float* w2    = (const float*)d_in[3];
    const float* bias2 = (const float*)d_in[4];
    const float* w3    = (const float*)d_in[5];
    const float* bias3 = (const float*)d_in[6];
    const float* s_in  = (const float*)d_in[7];
    const float* s1i   = (const float*)d_in[8];
    const float* s1o   = (const float*)d_in[9];
    const float* s2i   = (const float*)d_in[10];
    const float* s2o   = (const float*)d_in[11];
    const float* s3i   = (const float*)d_in[12];
    const float* s3o   = (const float*)d_in[13];

    float* out = (float*)d_out;
    // output order: (x_final, h0, h1, h2, h3)
    float* out0 = out;
    float* h0 = out + 655360;                   // 65536*10
    float* h1 = out + 52035584;                 // + 65536*784
    float* h2 = out + 60424192;                 // + 65536*128
    float* h3 = out + 68812800;                 // + 65536*128

    float* alphas  = (float*)d_ws;                        // 3 floats
    float* partial = (float*)((char*)d_ws + 16);          // 96 floats
    u16*   Wb1     = (u16*)((char*)d_ws + 512);           // 120832 u16

    alpha_part<<<96, 256, 0, stream>>>(w1, w2, w3, partial);
    alpha_final<<<1, 64, 0, stream>>>(partial, alphas);
    pack_kernel<<<472, 256, 0, stream>>>(w1, w2, w3, Wb1);
    fused_kernel<<<1024, 256, 0, stream>>>(input, bias1, bias2, bias3,
                                           s_in, s1i, s1o, s2i, s2o, s3i, s3o,
                                           alphas, Wb1,
                                           out0, h0, h1, h2, h3);
}

// Round 3
// 114.675 us; speedup vs baseline: 2.7417x; 1.0635x over previous
//
#include <hip/hip_runtime.h>
#include <math.h>

typedef __bf16 bf16x8 __attribute__((ext_vector_type(8)));
typedef float f32x4 __attribute__((ext_vector_type(4)));
typedef unsigned short u16;
typedef u16 u16x8 __attribute__((ext_vector_type(8)));

// clip(round(x*inv), -128, 127) -- rintf = round-half-even, matches jnp.round
__device__ __forceinline__ float quantq_inv(float x, float inv) {
    return fminf(fmaxf(rintf(x * inv), -128.f), 127.f);
}

__device__ __forceinline__ u16 sign_bf16(float w) {
    return (w > 0.f) ? (u16)0x3F80 : ((w < 0.f) ? (u16)0xBF80 : (u16)0);
}

// ---------------- prep 1a: per-slice |w| partial sums (deterministic) -------
__global__ void alpha_part(const float* __restrict__ w1,
                           const float* __restrict__ w2,
                           const float* __restrict__ w3,
                           float* __restrict__ partial) {
    __shared__ float red[256];
    const int bid = blockIdx.x;
    const int m = bid >> 5, i = bid & 31;
    const float* w = (m == 0) ? w1 : ((m == 1) ? w2 : w3);
    const int n = (m == 0) ? 100352 : ((m == 1) ? 16384 : 1280);
    const int chunk = n >> 5;  // all divisible by 32
    const float* p = w + i * chunk;
    float s = 0.f;
    for (int t = threadIdx.x; t < chunk; t += 256) s += fabsf(p[t]);
    red[threadIdx.x] = s;
    __syncthreads();
    for (int off = 128; off > 0; off >>= 1) {
        if ((int)threadIdx.x < off) red[threadIdx.x] += red[threadIdx.x + off];
        __syncthreads();
    }
    if (threadIdx.x == 0) partial[bid] = red[0];
}

// ---------------- prep 1b: final alpha = sum(partials)/n --------------------
__global__ void alpha_final(const float* __restrict__ partial,
                            float* __restrict__ alphas) {
    const int t = threadIdx.x;
    if (t < 3) {
        float s = 0.f;
        for (int i = 0; i < 32; ++i) s += partial[t * 32 + i];
        const int n = (t == 0) ? 100352 : ((t == 1) ? 16384 : 1280);
        alphas[t] = s / (float)n;
    }
}

// ---------------- prep 2: pack sign(w) as bf16 +-1, fragment-ready ----------
// dest layout per kstep(K=32): [ntile][lane][8] where for B-operand of
// mfma_f32_16x16x32_bf16: lane = (kk/8)*16 + (col%16), j = kk%8
// Wb1: K padded 784->800 (25 ksteps, 8 ntiles)   = 102400 u16
// Wb2: K=128 (4 ksteps, 8 ntiles)                =  16384 u16
// Wb3: K=128 (4 ksteps, 1 ntile), N padded 10->16 =  2048 u16
__global__ void pack_kernel(const float* __restrict__ w1,
                            const float* __restrict__ w2,
                            const float* __restrict__ w3,
                            u16* __restrict__ Wb1) {
    u16* Wb2 = Wb1 + 102400;
    u16* Wb3 = Wb2 + 16384;
    int idx = blockIdx.x * 256 + threadIdx.x;
    if (idx < 102400) {
        int k = idx >> 7, n = idx & 127;
        u16 v = (k < 784) ? sign_bf16(w1[k * 128 + n]) : (u16)0;
        int dest = ((((k >> 5) * 8 + (n >> 4)) * 64) + ((((k & 31) >> 3) << 4) | (n & 15))) * 8 + (k & 7);
        Wb1[dest] = v;
    } else if (idx < 102400 + 16384) {
        int i = idx - 102400;
        int k = i >> 7, n = i & 127;
        u16 v = sign_bf16(w2[k * 128 + n]);
        int dest = ((((k >> 5) * 8 + (n >> 4)) * 64) + ((((k & 31) >> 3) << 4) | (n & 15))) * 8 + (k & 7);
        Wb2[dest] = v;
    } else if (idx < 102400 + 16384 + 2048) {
        int i = idx - 102400 - 16384;
        int k = i >> 4, n = i & 15;
        u16 v = (n < 10) ? sign_bf16(w3[k * 10 + n]) : (u16)0;
        int dest = (((k >> 5) * 64) + ((((k & 31) >> 3) << 4) | n)) * 8 + (k & 7);
        Wb3[dest] = v;
    }
}

// ---------------- fused forward: 64 rows/block, 4 waves, ZERO barriers ------
__global__ __launch_bounds__(256, 4) void fused_kernel(
    const float* __restrict__ input,
    const float* __restrict__ bias1, const float* __restrict__ bias2,
    const float* __restrict__ bias3,
    const float* __restrict__ ps_in, const float* __restrict__ ps1i,
    const float* __restrict__ ps1o, const float* __restrict__ ps2i,
    const float* __restrict__ ps2o, const float* __restrict__ ps3i,
    const float* __restrict__ ps3o,
    const float* __restrict__ alphas, const u16* __restrict__ Wb1,
    float* __restrict__ out0, float* __restrict__ h0, float* __restrict__ h1,
    float* __restrict__ h2, float* __restrict__ h3)
{
    const u16* Wb2 = Wb1 + 102400;
    const u16* Wb3 = Wb2 + 16384;

    // wave-local inter-layer exchange only (no block barriers anywhere)
    __shared__ u16 A2[8192];  // [ks(4)][wave(4)][lane(64)][8] : 64 rows x 128 k

    const int tid = threadIdx.x;
    const int wave = tid >> 6, lane = tid & 63;
    const int row0 = blockIdx.x * 64;

    const float s_in = *ps_in, s1i = *ps1i, s1o = *ps1o;
    const float s2i = *ps2i, s2o = *ps2o, s3i = *ps3i, s3o = *ps3o;
    const float inv_sin = 1.f / s_in, inv_s1i = 1.f / s1i, inv_s1o = 1.f / s1o;
    const float inv_s2i = 1.f / s2i, inv_s2o = 1.f / s2o;
    const float inv_s3i = 1.f / s3i, inv_s3o = 1.f / s3o;
    const float alpha1 = alphas[0], alpha2 = alphas[1], alpha3 = alphas[2];

    // A-frag ownership: row = lane&15 (within wave's 16-row tile), kgroup = lane>>4
    const int rA = lane & 15;
    const int gA = lane >> 4;
    const size_t arow = (size_t)(row0 + wave * 16 + rA) * 784;
    const float* __restrict__ inA = input + arow + gA * 8;
    float* __restrict__ h0A = h0 + arow + gA * 8;
    const u16* bw1 = Wb1 + (size_t)lane * 8;

    f32x4 acc1[8];
#pragma unroll
    for (int n = 0; n < 8; ++n) acc1[n] = f32x4{0.f, 0.f, 0.f, 0.f};

    // quant + h0-store + pack + 8 MFMAs for one kstep's 8 owned elements
    auto consume = [&](int ksq, f32x4 va, f32x4 vb, bool dostore) {
        float q[8];
#pragma unroll
        for (int j = 0; j < 4; ++j) {
            q[j]     = quantq_inv(va[j], inv_sin);
            q[4 + j] = quantq_inv(vb[j], inv_sin);
        }
        if (dostore) {
            f32x4 ha = {q[0] * s_in, q[1] * s_in, q[2] * s_in, q[3] * s_in};
            f32x4 hb = {q[4] * s_in, q[5] * s_in, q[6] * s_in, q[7] * s_in};
            float* hp = h0A + ksq * 32;
            __builtin_nontemporal_store(ha, reinterpret_cast<f32x4*>(hp));
            __builtin_nontemporal_store(hb, reinterpret_cast<f32x4*>(hp + 4));
        }
        u16x8 qb;
#pragma unroll
        for (int j = 0; j < 8; ++j) qb[j] = (u16)(__float_as_uint(q[j]) >> 16);
        union { u16x8 u; bf16x8 b; } cvt;
        cvt.u = qb;
        const bf16x8 a = cvt.b;
        const u16* bp = bw1 + (size_t)ksq * 4096;
#pragma unroll
        for (int n = 0; n < 8; ++n) {
            const bf16x8 b = *reinterpret_cast<const bf16x8*>(bp + n * 512);
            acc1[n] = __builtin_amdgcn_mfma_f32_16x16x32_bf16(a, b, acc1[n], 0, 0, 0);
        }
    };

    // ---- layer 1: K=784 padded to 800 (25 ksteps), 4-deep static ring ------
    f32x4 s0a, s0b, s1a, s1b, s2a, s2b, s3a, s3b;
    s0a = *reinterpret_cast<const f32x4*>(inA + 0 * 32);
    s0b = *reinterpret_cast<const f32x4*>(inA + 0 * 32 + 4);
    s1a = *reinterpret_cast<const f32x4*>(inA + 1 * 32);
    s1b = *reinterpret_cast<const f32x4*>(inA + 1 * 32 + 4);
    s2a = *reinterpret_cast<const f32x4*>(inA + 2 * 32);
    s2b = *reinterpret_cast<const f32x4*>(inA + 2 * 32 + 4);
    s3a = *reinterpret_cast<const f32x4*>(inA + 3 * 32);
    s3b = *reinterpret_cast<const f32x4*>(inA + 3 * 32 + 4);

#define L1_STEP(K, SA, SB)                                                    \
    {                                                                         \
        f32x4 na, nb;                                                         \
        const int t_ = (K) + 4;                                               \
        if (t_ < 24) {                                                        \
            na = *reinterpret_cast<const f32x4*>(inA + t_ * 32);              \
            nb = *reinterpret_cast<const f32x4*>(inA + t_ * 32 + 4);          \
        } else if (t_ == 24) {                                                \
            if (gA < 2) {                                                     \
                na = *reinterpret_cast<const f32x4*>(inA + 768);              \
                nb = *reinterpret_cast<const f32x4*>(inA + 768 + 4);          \
            } else {                                                          \
                na = f32x4{0.f, 0.f, 0.f, 0.f};                               \
                nb = f32x4{0.f, 0.f, 0.f, 0.f};                               \
            }                                                                 \
        } else {                                                              \
            na = SA; nb = SB;                                                 \
        }                                                                     \
        consume((K), SA, SB, true);                                           \
        SA = na; SB = nb;                                                     \
    }

#pragma unroll
    for (int base = 0; base < 24; base += 4) {
        L1_STEP(base + 0, s0a, s0b);
        L1_STEP(base + 1, s1a, s1b);
        L1_STEP(base + 2, s2a, s2b);
        L1_STEP(base + 3, s3a, s3b);
    }
#undef L1_STEP

    // tail kstep ksq=24 (cols 768..800; valid only for gA<2, slots hold zeros
    // for gA>=2 so quant yields exact 0 -> qb=0)
    {
        float q[8];
#pragma unroll
        for (int j = 0; j < 4; ++j) {
            q[j]     = quantq_inv(s0a[j], inv_sin);
            q[4 + j] = quantq_inv(s0b[j], inv_sin);
        }
        if (gA < 2) {
            f32x4 ha = {q[0] * s_in, q[1] * s_in, q[2] * s_in, q[3] * s_in};
            f32x4 hb = {q[4] * s_in, q[5] * s_in, q[6] * s_in, q[7] * s_in};
            float* hp = h0A + 24 * 32;
            __builtin_nontemporal_store(ha, reinterpret_cast<f32x4*>(hp));
            __builtin_nontemporal_store(hb, reinterpret_cast<f32x4*>(hp + 4));
        }
        u16x8 qb;
#pragma unroll
        for (int j = 0; j < 8; ++j) qb[j] = (u16)(__float_as_uint(q[j]) >> 16);
        union { u16x8 u; bf16x8 b; } cvt;
        cvt.u = qb;
        const bf16x8 a = cvt.b;
        const u16* bp = bw1 + (size_t)24 * 4096;
#pragma unroll
        for (int n = 0; n < 8; ++n) {
            const bf16x8 b = *reinterpret_cast<const bf16x8*>(bp + n * 512);
            acc1[n] = __builtin_amdgcn_mfma_f32_16x16x32_bf16(a, b, acc1[n], 0, 0, 0);
        }
    }

    // ---- layer 1 epilogue: requantize, write h1, restage A2 (wave-local) ----
    const int cl = lane & 15;
    const int rh = lane >> 4;
    {
        const float a1s = alpha1 * s_in;
#pragma unroll
        for (int n = 0; n < 8; ++n) {
            const int col = n * 16 + cl;
            const float bias = bias1[col];
            const int ks = n >> 1;
            const int gk = ((n & 1) * 2) + (cl >> 3);
            const int jd = cl & 7;
#pragma unroll
            for (int j = 0; j < 4; ++j) {
                const int rl = rh * 4 + j;
                float x = a1s * acc1[n][j] + bias;
                x = quantq_inv(x, inv_s1i) * s1i;
                x = fmaxf(x, 0.f);
                const float qv = quantq_inv(x, inv_s1o);
                __builtin_nontemporal_store(qv * s1o,
                    h1 + (size_t)(row0 + wave * 16 + rl) * 128 + col);
                A2[(((ks * 4 + wave) * 64) + (gk * 16 + rl)) * 8 + jd] =
                    (u16)(__float_as_uint(qv) >> 16);
            }
        }
    }

    // ---- layer 2: K=128 (4 ksteps), B-frags straight from global (L1) ----
    f32x4 acc2[8];
#pragma unroll
    for (int n = 0; n < 8; ++n) acc2[n] = f32x4{0.f, 0.f, 0.f, 0.f};
#pragma unroll
    for (int ks = 0; ks < 4; ++ks) {
        const bf16x8 a = *reinterpret_cast<const bf16x8*>(&A2[((ks * 4 + wave) * 64 + lane) * 8]);
#pragma unroll
        for (int n = 0; n < 8; ++n) {
            const bf16x8 b = *reinterpret_cast<const bf16x8*>(Wb2 + ((size_t)(ks * 8 + n) * 64 + lane) * 8);
            acc2[n] = __builtin_amdgcn_mfma_f32_16x16x32_bf16(a, b, acc2[n], 0, 0, 0);
        }
    }

    // ---- layer 2 epilogue ----
    {
        const float a2s = alpha2 * s1o;
#pragma unroll
        for (int n = 0; n < 8; ++n) {
            const int col = n * 16 + cl;
            const float bias = bias2[col];
            const int ks = n >> 1;
            const int gk = ((n & 1) * 2) + (cl >> 3);
            const int jd = cl & 7;
#pragma unroll
            for (int j = 0; j < 4; ++j) {
                const int rl = rh * 4 + j;
                float x = a2s * acc2[n][j] + bias;
                x = quantq_inv(x, inv_s2i) * s2i;
                x = fmaxf(x, 0.f);
                const float qv = quantq_inv(x, inv_s2o);
                __builtin_nontemporal_store(qv * s2o,
                    h2 + (size_t)(row0 + wave * 16 + rl) * 128 + col);
                A2[(((ks * 4 + wave) * 64) + (gk * 16 + rl)) * 8 + jd] =
                    (u16)(__float_as_uint(qv) >> 16);
            }
        }
    }

    // ---- layer 3: K=128, single ntile (N=10 padded to 16) ----
    f32x4 acc3 = f32x4{0.f, 0.f, 0.f, 0.f};
#pragma unroll
    for (int ks = 0; ks < 4; ++ks) {
        const bf16x8 a = *reinterpret_cast<const bf16x8*>(&A2[((ks * 4 + wave) * 64 + lane) * 8]);
        const bf16x8 b = *reinterpret_cast<const bf16x8*>(Wb3 + ((size_t)ks * 64 + lane) * 8);
        acc3 = __builtin_amdgcn_mfma_f32_16x16x32_bf16(a, b, acc3, 0, 0, 0);
    }

    // ---- layer 3 epilogue: sigmoid + quant, write h3 and out0 ----
    if (cl < 10) {
        const float a3s = alpha3 * s2o;
        const float bias = bias3[cl];
#pragma unroll
        for (int j = 0; j < 4; ++j) {
            const int rgl = row0 + wave * 16 + rh * 4 + j;
            float x = a3s * acc3[j] + bias;
            x = quantq_inv(x, inv_s3i) * s3i;
            const float sg = 1.f / (1.f + expf(-x));
            const float qv = quantq_inv(sg, inv_s3o) * s3o;
            out0[(size_t)rgl * 10 + cl] = qv;
            h3[(size_t)rgl * 10 + cl] = qv;
        }
    }
}

extern "C" void kernel_launch(void* const* d_in, const int* in_sizes, int n_in,
                              void* d_out, int out_size, void* d_ws, size_t ws_size,
                              hipStream_t stream) {
    const float* input = (const float*)d_in[0];
    const float* w1    = (const float*)d_in[1];
    const float* bias1 = (const float*)d_in[2];
    const float* w2    = (const float*)d_in[3];
    const float* bias2 = (const float*)d_in[4];
    const float* w3    = (const float*)d_in[5];
    const float* bias3 = (const float*)d_in[6];
    const float* s_in  = (const float*)d_in[7];
    const float* s1i   = (const float*)d_in[8];
    const float* s1o   = (const float*)d_in[9];
    const float* s2i   = (const float*)d_in[10];
    const float* s2o   = (const float*)d_in[11];
    const float* s3i   = (const float*)d_in[12];
    const float* s3o   = (const float*)d_in[13];

    float* out = (float*)d_out;
    // output order: (x_final, h0, h1, h2, h3)
    float* out0 = out;
    float* h0 = out + 655360;                   // 65536*10
    float* h1 = out + 52035584;                 // + 65536*784
    float* h2 = out + 60424192;                 // + 65536*128
    float* h3 = out + 68812800;                 // + 65536*128

    float* alphas  = (float*)d_ws;                        // 3 floats
    float* partial = (float*)((char*)d_ws + 16);          // 96 floats
    u16*   Wb1     = (u16*)((char*)d_ws + 512);           // 120832 u16

    alpha_part<<<96, 256, 0, stream>>>(w1, w2, w3, partial);
    alpha_final<<<1, 64, 0, stream>>>(partial, alphas);
    pack_kernel<<<472, 256, 0, stream>>>(w1, w2, w3, Wb1);
    fused_kernel<<<1024, 256, 0, stream>>>(input, bias1, bias2, bias3,
                                           s_in, s1i, s1o, s2i, s2o, s3i, s3o,
                                           alphas, Wb1,
                                           out0, h0, h1, h2, h3);
}